// Round 2
// baseline (175.825 us; speedup 1.0000x reference)
//
#include <hip/hip_runtime.h>
#include <math.h>
#include <float.h>

// Problem constants (fixed by the reference)
#define Bn   64
#define Sn   512
#define FWn  6
#define Wn   507     // S - FW + 1
#define WT   32      // windows per block (2 sub-tiles of 16)
#define NTILE 16     // 507 windows -> 16 tiles of 32

#define PROWS   37    // projection rows per block (32 windows + FW-1)
#define PSTRIDE 512   // fp16 elems per Pt row (1024 B). R10 verified: stride-512
                      // is phase-conflict-free (SQ_LDS_BANK_CONFLICT ~1.7% of
                      // cycles). LDS total 53 KiB -> 3 blocks/CU by LDS.

typedef __attribute__((ext_vector_type(8))) _Float16 half8;
typedef __attribute__((ext_vector_type(4))) _Float16 half4;
typedef __attribute__((ext_vector_type(4))) float f32x4;

// Fast activations: v_exp_f32 + v_rcp_f32 (1 ulp), NaN-free at extremes.
__device__ __forceinline__ float sigf(float x)  {
    return __builtin_amdgcn_rcpf(1.0f + __expf(-x));
}
__device__ __forceinline__ float tanh_(float x) {
    return 1.0f - 2.0f * __builtin_amdgcn_rcpf(__expf(2.0f * x) + 1.0f);
}

// ---------------------------------------------------------------------------
// Kernel 0: pack w_ih and w_hh (both [512][128] f32) into fp16 B-fragment
// order for mfma_f32_16x16x32_f16:
//   pack[((nt*4 + ks)*64 + lane)*8 + j] = w[nt*16 + (lane&15)][ks*32 + (lane>>4)*8 + j]
// Row-tile nt = g*8 + ut (gate g, unit-tile ut). 65536 elements each.
// ---------------------------------------------------------------------------
__global__ void __launch_bounds__(256)
pack_w_kernel(const float* __restrict__ w_ih, const float* __restrict__ w_hh,
              _Float16* __restrict__ wih_p, _Float16* __restrict__ whh_p)
{
    const int idx = blockIdx.x * 256 + threadIdx.x;      // 0..65535
    const int j  = idx & 7;
    const int L  = (idx >> 3) & 63;
    const int ks = (idx >> 9) & 3;
    const int nt = idx >> 11;
    const int row = nt * 16 + (L & 15);
    const int col = ks * 32 + (L >> 4) * 8 + j;
    wih_p[idx] = (_Float16)w_ih[row * 128 + col];
    whh_p[idx] = (_Float16)w_hh[row * 128 + col];
}

// ---------------------------------------------------------------------------
// Kernel 1 (fused MFMA LSTM), 32 windows (2 sub-tiles) per 512-thread block.
//   R10 finding: VGPR=68 crossed the 64-VGPR occupancy cliff (waves/SIMD
//   halve above 64 — m69), capping residency at 2 blocks/CU and making the
//   LDS shave moot. R10 lever: __launch_bounds__(512, 8) pins VGPR<=64
//   (8 waves/EU capable; LDS then binds at 3 blocks/CU = 24 waves/CU).
//   Structural pressure cuts so the cap doesn't spill (R3 hazard):
//     - phase 1 is mt-OUTER (one 16-row m-tile at a time: peak ~45 live
//       regs vs ~75 for the old 3-tile accx[3][4] scheme);
//     - no whf[4][4] "register-resident" array: 64 VGPRs of fp16 never fit
//       in a 68-VGPR kernel — the compiler was reloading from global per
//       use anyway. B-fragments now load inline in the step loop.
//   Phase 2: 6 steps x {2 sub-tiles}; h via 4 KB/sub double-buffered
//   A-frag LDS; 1 barrier/step.
// grid 64*16, block 512.
// ---------------------------------------------------------------------------
__global__ void __launch_bounds__(512, 8)
lstm_kernel(const int* __restrict__ inputs, const float* __restrict__ embed,
            const _Float16* __restrict__ wih_p, const _Float16* __restrict__ whh_p,
            const float* __restrict__ b_ih, const float* __restrict__ b_hh,
            float* __restrict__ partial)
{
    __shared__ __align__(16) _Float16 Pt[PROWS * PSTRIDE];  // 37 KiB
    __shared__ __align__(16) _Float16 hsA[2][2][2048];      // 16 KiB
    const int t    = threadIdx.x;
    const int L    = t & 63;
    const int ut   = t >> 6;          // wave index = unit-tile 0..7
    const int b    = blockIdx.x >> 4;
    const int tile = blockIdx.x & 15;
    const int w0   = tile * WT;
    const int q  = L >> 4;
    const int ln = L & 15;
    const int j8 = L & 7;
    const int u  = ut * 16 + ln;      // this lane's hidden unit (B n-index)

    // ---- phase 1: x-proj, one 16-row m-tile at a time (low reg pressure) ----
    {
        float bg[4];
#pragma unroll
        for (int g = 0; g < 4; ++g)
            bg[g] = b_ih[g * 128 + u] + b_hh[g * 128 + u];
        int tok[3];
#pragma unroll
        for (int mt = 0; mt < 3; ++mt) {
            int s = w0 + mt * 16 + ln; s = s < 511 ? s : 511;  // clamp (masked at max)
            tok[mt] = inputs[b * Sn + s];
        }
#pragma unroll
        for (int mt = 0; mt < 3; ++mt) {
            f32x4 acc[4];   // [gate], init with bias
#pragma unroll
            for (int g = 0; g < 4; ++g)
                acc[g] = (f32x4){bg[g], bg[g], bg[g], bg[g]};
#pragma unroll
            for (int ks = 0; ks < 4; ++ks) {
                const float* er = embed + (size_t)tok[mt] * 128 + ks * 32 + q * 8;
                float4 e0 = *(const float4*)er;
                float4 e1 = *(const float4*)(er + 4);
                half8 a;
                a[0] = (_Float16)e0.x; a[1] = (_Float16)e0.y;
                a[2] = (_Float16)e0.z; a[3] = (_Float16)e0.w;
                a[4] = (_Float16)e1.x; a[5] = (_Float16)e1.y;
                a[6] = (_Float16)e1.z; a[7] = (_Float16)e1.w;
#pragma unroll
                for (int g = 0; g < 4; ++g) {
                    half8 bw = *(const half8*)(wih_p + ((size_t)((g * 8 + ut) * 4 + ks) * 64 + L) * 8);
                    acc[g] = __builtin_amdgcn_mfma_f32_16x16x32_f16(a, bw, acc[g], 0, 0, 0);
                }
            }
            // store gate-interleaved fp16 Pt rows (predicated to 37 rows)
#pragma unroll
            for (int r = 0; r < 4; ++r) {
                const int sl = mt * 16 + q * 4 + r;
                if (sl < PROWS) {
                    half4 o;
                    o[0] = (_Float16)acc[0][r];
                    o[1] = (_Float16)acc[1][r];
                    o[2] = (_Float16)acc[2][r];
                    o[3] = (_Float16)acc[3][r];
                    *(half4*)&Pt[sl * PSTRIDE + u * 4] = o;
                }
            }
        }
    }

    __syncthreads();    // Pt visible to all waves

    // h scatter address components (A-fragment layout for unit u, window m)
    const int ks_h = ut >> 1;
    const int qp   = (ut & 1) * 2 + (ln >> 3);

    float cst[2][4] = {{0.f, 0.f, 0.f, 0.f}, {0.f, 0.f, 0.f, 0.f}};
    float hh[2][4];

    // ---- steps 0..5, two independent sub-tiles per barrier interval ----
    for (int st = 0; st < FWn; ++st) {
        if (st > 0) __syncthreads();        // prev step's h scatter visible
#pragma unroll
        for (int sub = 0; sub < 2; ++sub) {
            f32x4 acc[4];                   // [gate] over r
#pragma unroll
            for (int r = 0; r < 4; ++r) {
                half4 pv = *(const half4*)&Pt[(sub * 16 + q * 4 + r + st) * PSTRIDE + u * 4];
                acc[0][r] = (float)pv[0]; acc[1][r] = (float)pv[1];
                acc[2][r] = (float)pv[2]; acc[3][r] = (float)pv[3];
            }
            if (st > 0) {
                const _Float16* hb = hsA[(st + 1) & 1][sub];   // h(st-1)
#pragma unroll
                for (int ks = 0; ks < 4; ++ks) {
                    half8 ah = *(const half8*)(hb + (ks * 64 + L) * 8);
#pragma unroll
                    for (int g = 0; g < 4; ++g) {
                        half8 bw = *(const half8*)(whh_p + ((size_t)((g * 8 + ut) * 4 + ks) * 64 + L) * 8);
                        acc[g] = __builtin_amdgcn_mfma_f32_16x16x32_f16(ah, bw, acc[g], 0, 0, 0);
                    }
                }
            }
            _Float16* buf = hsA[st & 1][sub];
#pragma unroll
            for (int r = 0; r < 4; ++r) {
                float ii = sigf(acc[0][r]);
                float ff = sigf(acc[1][r]);
                float gg = tanh_(acc[2][r]);
                float oo = sigf(acc[3][r]);
                float cc = ff * cst[sub][r] + ii * gg;
                cst[sub][r] = cc;
                hh[sub][r] = oo * tanh_(cc);
                if (st < FWn - 1)
                    buf[ks_h * 512 + (qp * 16 + q * 4 + r) * 8 + j8] = (_Float16)hh[sub][r];
            }
        }
    }

    // ---- max over this block's 32 windows (mask invalid), reduce across q ----
    float mv = -FLT_MAX;
#pragma unroll
    for (int sub = 0; sub < 2; ++sub)
#pragma unroll
        for (int r = 0; r < 4; ++r) {
            const int w = w0 + sub * 16 + q * 4 + r;
            if (w < Wn) mv = fmaxf(mv, hh[sub][r]);
        }
    mv = fmaxf(mv, __shfl_xor(mv, 16));
    mv = fmaxf(mv, __shfl_xor(mv, 32));
    if (q == 0)
        partial[(size_t)(b * NTILE + tile) * 128 + u] = mv;
}

// ---------------------------------------------------------------------------
// Kernel 2: feat[b][u] = max over tiles; out[b][c] = feat . fc_w[c] + fc_b[c]
// grid 64, block 128
// ---------------------------------------------------------------------------
__global__ void __launch_bounds__(128)
final_kernel(const float* __restrict__ partial, const float* __restrict__ fc_w,
             const float* __restrict__ fc_b, float* __restrict__ out)
{
    const int b = blockIdx.x;
    const int u = threadIdx.x;
    float m = -FLT_MAX;
#pragma unroll
    for (int tl = 0; tl < NTILE; ++tl)
        m = fmaxf(m, partial[(size_t)(b * NTILE + tl) * 128 + u]);
    float v0 = m * fc_w[u];
    float v1 = m * fc_w[128 + u];
#pragma unroll
    for (int off = 1; off < 64; off <<= 1) {
        v0 += __shfl_xor(v0, off);
        v1 += __shfl_xor(v1, off);
    }
    __shared__ float red[2][2];
    if ((u & 63) == 0) { red[u >> 6][0] = v0; red[u >> 6][1] = v1; }
    __syncthreads();
    if (u == 0) {
        out[b * 2 + 0] = red[0][0] + red[1][0] + fc_b[0];
        out[b * 2 + 1] = red[0][1] + red[1][1] + fc_b[1];
    }
}

// ---------------------------------------------------------------------------
extern "C" void kernel_launch(void* const* d_in, const int* in_sizes, int n_in,
                              void* d_out, int out_size, void* d_ws, size_t ws_size,
                              hipStream_t stream)
{
    const int*   inputs = (const int*)d_in[0];
    // d_in[1] = lengths : unused by the reference
    const float* embed  = (const float*)d_in[2];
    const float* w_ih   = (const float*)d_in[3];
    const float* w_hh   = (const float*)d_in[4];
    const float* b_ih   = (const float*)d_in[5];
    const float* b_hh   = (const float*)d_in[6];
    const float* fc_w   = (const float*)d_in[7];
    const float* fc_b   = (const float*)d_in[8];
    float* out = (float*)d_out;

    // workspace: partial (512 KiB) | wih_p, whh_p (128 KiB each)
    float*    partial = (float*)d_ws;
    _Float16* wih_p   = (_Float16*)(partial + Bn * NTILE * 128);
    _Float16* whh_p   = wih_p + 65536;

    pack_w_kernel<<<dim3(256), 256, 0, stream>>>(w_ih, w_hh, wih_p, whh_p);
    lstm_kernel<<<dim3(Bn * NTILE), 512, 0, stream>>>(inputs, embed, wih_p, whh_p,
                                                      b_ih, b_hh, partial);
    final_kernel<<<dim3(Bn), 128, 0, stream>>>(partial, fc_w, fc_b, out);
}

// Round 3
// 141.120 us; speedup vs baseline: 1.2459x; 1.2459x over previous
//
#include <hip/hip_runtime.h>
#include <math.h>
#include <float.h>

// Problem constants (fixed by the reference)
#define Bn   64
#define Sn   512
#define FWn  6
#define Wn   507     // S - FW + 1
#define WT   32      // windows per block (2 sub-tiles of 16)
#define NTILE 16     // 507 windows -> 16 tiles of 32

#define PROWS   37    // projection rows per block (32 windows + FW-1)
#define PSTRIDE 512   // fp16 elems per Pt row (1024 B). R10 verified stride-512
                      // phase-conflict-free (SQ_LDS_BANK_CONFLICT ~1.7%).

typedef __attribute__((ext_vector_type(8))) _Float16 half8;
typedef __attribute__((ext_vector_type(4))) _Float16 half4;
typedef __attribute__((ext_vector_type(4))) float f32x4;

// Fast activations: v_exp_f32 + v_rcp_f32 (1 ulp), NaN-free at extremes.
__device__ __forceinline__ float sigf(float x)  {
    return __builtin_amdgcn_rcpf(1.0f + __expf(-x));
}
__device__ __forceinline__ float tanh_(float x) {
    return 1.0f - 2.0f * __builtin_amdgcn_rcpf(__expf(2.0f * x) + 1.0f);
}

// ---------------------------------------------------------------------------
// Kernel 0: pack w_ih and w_hh (both [512][128] f32) into fp16 B-fragment
// order for mfma_f32_16x16x32_f16:
//   pack[((nt*4 + ks)*64 + lane)*8 + j] = w[nt*16 + (lane&15)][ks*32 + (lane>>4)*8 + j]
// Row-tile nt = g*8 + ut (gate g, unit-tile ut). 65536 elements each.
// ---------------------------------------------------------------------------
__global__ void __launch_bounds__(256)
pack_w_kernel(const float* __restrict__ w_ih, const float* __restrict__ w_hh,
              _Float16* __restrict__ wih_p, _Float16* __restrict__ whh_p)
{
    const int idx = blockIdx.x * 256 + threadIdx.x;      // 0..65535
    const int j  = idx & 7;
    const int L  = (idx >> 3) & 63;
    const int ks = (idx >> 9) & 3;
    const int nt = idx >> 11;
    const int row = nt * 16 + (L & 15);
    const int col = ks * 32 + (L >> 4) * 8 + j;
    wih_p[idx] = (_Float16)w_ih[row * 128 + col];
    whh_p[idx] = (_Float16)w_hh[row * 128 + col];
}

// ---------------------------------------------------------------------------
// Kernel 1 (fused MFMA LSTM), 32 windows (2 sub-tiles) per 512-thread block.
//   R11 post-mortem: kernel is CRITICAL-PATH-bound, not residency-bound
//   (R11 raised occupancy 21.7->40.7% yet ran 28% slower; VALU issue-cycles
//   conserved). The path-length killers were (a) whh B-fragment global
//   loads inside the serial 6-step recurrence, (b) phase-1 ILP loss.
//   R12: __launch_bounds__(512, 4) -> 128-VGPR budget, which lets the
//   allocator keep whf[4][4] (64 VGPRs) genuinely register-resident.
//   whf loads issue just before the phase-1->phase-2 barrier; step 0 does
//   not use whf, so one full step of slack covers the one-time latency.
//   Phase 1: mt-INNER, 3 independent accumulator streams (ILP hides MFMA
//   latency — measured-good in R10).
//   Phase 2: 6 steps x {2 sub-tiles}; whh register-resident; h via 4 KB/sub
//   double-buffered A-frag LDS; 1 barrier/step; ZERO global loads.
//   NOTE: (512,4) RAISES the register budget (R3's spill hazard was a
//   high-min-waves bound, i.e. a forced LOW budget).
// grid 64*16, block 512.
// ---------------------------------------------------------------------------
__global__ void __launch_bounds__(512, 4)
lstm_kernel(const int* __restrict__ inputs, const float* __restrict__ embed,
            const _Float16* __restrict__ wih_p, const _Float16* __restrict__ whh_p,
            const float* __restrict__ b_ih, const float* __restrict__ b_hh,
            float* __restrict__ partial)
{
    __shared__ __align__(16) _Float16 Pt[PROWS * PSTRIDE];  // 37 KiB
    __shared__ __align__(16) _Float16 hsA[2][2][2048];      // 16 KiB
    const int t    = threadIdx.x;
    const int L    = t & 63;
    const int ut   = t >> 6;          // wave index = unit-tile 0..7
    const int b    = blockIdx.x >> 4;
    const int tile = blockIdx.x & 15;
    const int w0   = tile * WT;
    const int q  = L >> 4;
    const int ln = L & 15;
    const int j8 = L & 7;
    const int u  = ut * 16 + ln;      // this lane's hidden unit (B n-index)

    // ---- phase 1: x-proj (3 m-tiles = rows 0..47, stores clamped to 37) ----
    {
        f32x4 accx[3][4];   // [mt][gate], init with bias
#pragma unroll
        for (int g = 0; g < 4; ++g) {
            const float bg = b_ih[g * 128 + u] + b_hh[g * 128 + u];
            accx[0][g] = (f32x4){bg, bg, bg, bg};
            accx[1][g] = accx[0][g];
            accx[2][g] = accx[0][g];
        }
        int tok[3];
#pragma unroll
        for (int mt = 0; mt < 3; ++mt) {
            int s = w0 + mt * 16 + ln; s = s < 511 ? s : 511;  // clamp (masked at max)
            tok[mt] = inputs[b * Sn + s];
        }
#pragma unroll
        for (int ks = 0; ks < 4; ++ks) {
            half8 ax[3];
#pragma unroll
            for (int mt = 0; mt < 3; ++mt) {
                const float* er = embed + (size_t)tok[mt] * 128 + ks * 32 + q * 8;
                float4 e0 = *(const float4*)er;
                float4 e1 = *(const float4*)(er + 4);
                half8 a;
                a[0] = (_Float16)e0.x; a[1] = (_Float16)e0.y;
                a[2] = (_Float16)e0.z; a[3] = (_Float16)e0.w;
                a[4] = (_Float16)e1.x; a[5] = (_Float16)e1.y;
                a[6] = (_Float16)e1.z; a[7] = (_Float16)e1.w;
                ax[mt] = a;
            }
#pragma unroll
            for (int g = 0; g < 4; ++g) {
                half8 bw = *(const half8*)(wih_p + ((size_t)((g * 8 + ut) * 4 + ks) * 64 + L) * 8);
#pragma unroll
                for (int mt = 0; mt < 3; ++mt)
                    accx[mt][g] = __builtin_amdgcn_mfma_f32_16x16x32_f16(ax[mt], bw, accx[mt][g], 0, 0, 0);
            }
        }
        // store gate-interleaved fp16 Pt rows (predicated to 37 rows)
#pragma unroll
        for (int mt = 0; mt < 3; ++mt)
#pragma unroll
            for (int r = 0; r < 4; ++r) {
                const int sl = mt * 16 + q * 4 + r;
                if (sl < PROWS) {
                    half4 o;
                    o[0] = (_Float16)accx[mt][0][r];
                    o[1] = (_Float16)accx[mt][1][r];
                    o[2] = (_Float16)accx[mt][2][r];
                    o[3] = (_Float16)accx[mt][3][r];
                    *(half4*)&Pt[sl * PSTRIDE + u * 4] = o;
                }
            }
    }

    // register-resident w_hh B-fragments for this wave's unit-tile.
    // 64 VGPRs; loaded ONCE here. First use is step 1 (step 0 has no h-MFMA),
    // so the barrier below plus step 0 hide the load latency.
    half8 whf[4][4];    // [gate][ks]
#pragma unroll
    for (int g = 0; g < 4; ++g)
#pragma unroll
        for (int ks = 0; ks < 4; ++ks)
            whf[g][ks] = *(const half8*)(whh_p + ((size_t)((g * 8 + ut) * 4 + ks) * 64 + L) * 8);

    __syncthreads();    // Pt visible to all waves

    // h scatter address components (A-fragment layout for unit u, window m)
    const int ks_h = ut >> 1;
    const int qp   = (ut & 1) * 2 + (ln >> 3);

    float cst[2][4] = {{0.f, 0.f, 0.f, 0.f}, {0.f, 0.f, 0.f, 0.f}};
    float hh[2][4];

    // ---- steps 0..5, two independent sub-tiles per barrier interval ----
    for (int st = 0; st < FWn; ++st) {
        if (st > 0) __syncthreads();        // prev step's h scatter visible
#pragma unroll
        for (int sub = 0; sub < 2; ++sub) {
            f32x4 acc[4];                   // [gate] over r
#pragma unroll
            for (int r = 0; r < 4; ++r) {
                half4 pv = *(const half4*)&Pt[(sub * 16 + q * 4 + r + st) * PSTRIDE + u * 4];
                acc[0][r] = (float)pv[0]; acc[1][r] = (float)pv[1];
                acc[2][r] = (float)pv[2]; acc[3][r] = (float)pv[3];
            }
            if (st > 0) {
                const _Float16* hb = hsA[(st + 1) & 1][sub];   // h(st-1)
#pragma unroll
                for (int ks = 0; ks < 4; ++ks) {
                    half8 ah = *(const half8*)(hb + (ks * 64 + L) * 8);
#pragma unroll
                    for (int g = 0; g < 4; ++g)
                        acc[g] = __builtin_amdgcn_mfma_f32_16x16x32_f16(ah, whf[g][ks], acc[g], 0, 0, 0);
                }
            }
            _Float16* buf = hsA[st & 1][sub];
#pragma unroll
            for (int r = 0; r < 4; ++r) {
                float ii = sigf(acc[0][r]);
                float ff = sigf(acc[1][r]);
                float gg = tanh_(acc[2][r]);
                float oo = sigf(acc[3][r]);
                float cc = ff * cst[sub][r] + ii * gg;
                cst[sub][r] = cc;
                hh[sub][r] = oo * tanh_(cc);
                if (st < FWn - 1)
                    buf[ks_h * 512 + (qp * 16 + q * 4 + r) * 8 + j8] = (_Float16)hh[sub][r];
            }
        }
    }

    // ---- max over this block's 32 windows (mask invalid), reduce across q ----
    float mv = -FLT_MAX;
#pragma unroll
    for (int sub = 0; sub < 2; ++sub)
#pragma unroll
        for (int r = 0; r < 4; ++r) {
            const int w = w0 + sub * 16 + q * 4 + r;
            if (w < Wn) mv = fmaxf(mv, hh[sub][r]);
        }
    mv = fmaxf(mv, __shfl_xor(mv, 16));
    mv = fmaxf(mv, __shfl_xor(mv, 32));
    if (q == 0)
        partial[(size_t)(b * NTILE + tile) * 128 + u] = mv;
}

// ---------------------------------------------------------------------------
// Kernel 2: feat[b][u] = max over tiles; out[b][c] = feat . fc_w[c] + fc_b[c]
// grid 64, block 128
// ---------------------------------------------------------------------------
__global__ void __launch_bounds__(128)
final_kernel(const float* __restrict__ partial, const float* __restrict__ fc_w,
             const float* __restrict__ fc_b, float* __restrict__ out)
{
    const int b = blockIdx.x;
    const int u = threadIdx.x;
    float m = -FLT_MAX;
#pragma unroll
    for (int tl = 0; tl < NTILE; ++tl)
        m = fmaxf(m, partial[(size_t)(b * NTILE + tl) * 128 + u]);
    float v0 = m * fc_w[u];
    float v1 = m * fc_w[128 + u];
#pragma unroll
    for (int off = 1; off < 64; off <<= 1) {
        v0 += __shfl_xor(v0, off);
        v1 += __shfl_xor(v1, off);
    }
    __shared__ float red[2][2];
    if ((u & 63) == 0) { red[u >> 6][0] = v0; red[u >> 6][1] = v1; }
    __syncthreads();
    if (u == 0) {
        out[b * 2 + 0] = red[0][0] + red[1][0] + fc_b[0];
        out[b * 2 + 1] = red[0][1] + red[1][1] + fc_b[1];
    }
}

// ---------------------------------------------------------------------------
extern "C" void kernel_launch(void* const* d_in, const int* in_sizes, int n_in,
                              void* d_out, int out_size, void* d_ws, size_t ws_size,
                              hipStream_t stream)
{
    const int*   inputs = (const int*)d_in[0];
    // d_in[1] = lengths : unused by the reference
    const float* embed  = (const float*)d_in[2];
    const float* w_ih   = (const float*)d_in[3];
    const float* w_hh   = (const float*)d_in[4];
    const float* b_ih   = (const float*)d_in[5];
    const float* b_hh   = (const float*)d_in[6];
    const float* fc_w   = (const float*)d_in[7];
    const float* fc_b   = (const float*)d_in[8];
    float* out = (float*)d_out;

    // workspace: partial (512 KiB) | wih_p, whh_p (128 KiB each)
    float*    partial = (float*)d_ws;
    _Float16* wih_p   = (_Float16*)(partial + Bn * NTILE * 128);
    _Float16* whh_p   = wih_p + 65536;

    pack_w_kernel<<<dim3(256), 256, 0, stream>>>(w_ih, w_hh, wih_p, whh_p);
    lstm_kernel<<<dim3(Bn * NTILE), 512, 0, stream>>>(inputs, embed, wih_p, whh_p,
                                                      b_ih, b_hh, partial);
    final_kernel<<<dim3(Bn), 128, 0, stream>>>(partial, fc_w, fc_b, out);
}